// Round 4
// baseline (231.013 us; speedup 1.0000x reference)
//
#include <hip/hip_runtime.h>
#include <math.h>

#define BSZ    4
#define NTOK   6400      // 40*160
#define DMODEL 256
#define NHEAD  8
#define HDIM   32
#define NPTS   9
#define HSP    40
#define WSP    160
#define KDIM   256
#define MTOT   (BSZ*NTOK)   // 25600
#define NFUSED 912          // 256 q + 144 off + 512 kv

typedef short  short8  __attribute__((ext_vector_type(8)));
typedef float  floatx4 __attribute__((ext_vector_type(4)));

__device__ __forceinline__ ushort f2bf(float f) {
    uint u = __float_as_uint(f);
    u = (u + 0x7FFFu + ((u >> 16) & 1u)) >> 16;   // RNE
    return (ushort)u;
}

// unpack 8 packed bf16 (uint4) -> 8 fp32, 1 VALU/elem
__device__ __forceinline__ void unpack8(uint4 u, float* f) {
    f[0] = __uint_as_float(u.x << 16); f[1] = __uint_as_float(u.x & 0xFFFF0000u);
    f[2] = __uint_as_float(u.y << 16); f[3] = __uint_as_float(u.y & 0xFFFF0000u);
    f[4] = __uint_as_float(u.z << 16); f[5] = __uint_as_float(u.z & 0xFFFF0000u);
    f[6] = __uint_as_float(u.w << 16); f[7] = __uint_as_float(u.w & 0xFFFF0000u);
}

#define AS1C(p) ((const __attribute__((address_space(1))) void*)(p))
#define AS3(p)  ((__attribute__((address_space(3))) void*)(p))

// ---------------------------------------------------------------------------
// All fp32->bf16 casts in one launch. Block = 1024 elems.
// x 6400 | Wq 64 | Woff 36 | Wkv 128 | Wout 64 => 6692 blocks.
// Wq/Woff/Wkv write contiguously -> fused (912,256) weight matrix.
// ---------------------------------------------------------------------------
__global__ __launch_bounds__(256) void cast_all(
    const float* __restrict__ x,   const float* __restrict__ Wq,
    const float* __restrict__ Woff,const float* __restrict__ Wkv,
    const float* __restrict__ Wout,
    ushort* __restrict__ xb, ushort* __restrict__ wfused, ushort* __restrict__ woutb)
{
    const int bid = blockIdx.x;
    const float* src; ushort* dst; int base;
    if      (bid < 6400) { src = x;    dst = xb;              base = bid; }
    else if (bid < 6464) { src = Wq;   dst = wfused;          base = bid - 6400; }
    else if (bid < 6500) { src = Woff; dst = wfused + 65536;  base = bid - 6464; }
    else if (bid < 6628) { src = Wkv;  dst = wfused + 102400; base = bid - 6500; }
    else                 { src = Wout; dst = woutb;           base = bid - 6628; }
    const int i = base * 1024 + threadIdx.x * 4;
    float4 v = *(const float4*)(src + i);
    ushort4 o;
    o.x = f2bf(v.x); o.y = f2bf(v.y); o.z = f2bf(v.z); o.w = f2bf(v.w);
    *(ushort4*)(dst + i) = o;
}

// ---------------------------------------------------------------------------
// Fused input GEMM: [q | offsets | kv] = xb @ Wfused^T + bias.
// 128x128 tile, 4 waves (2x2), 4x4 frags of mfma 16x16x32 bf16.
// Epilogue dispatch by column: [0,256) q bf16 | [256,400) tanh*4 fp32 |
// [400,912) kv scatter into interleaved (B*H, N, 64) | >=912 dead.
// ---------------------------------------------------------------------------
__global__ __launch_bounds__(256) void gemm_fused(
    const ushort* __restrict__ Xb,
    const ushort* __restrict__ Wb,
    const float* __restrict__ bq, const float* __restrict__ boff,
    const float* __restrict__ bkv,
    ushort* __restrict__ qb, float* __restrict__ off, ushort* __restrict__ kvb)
{
    __shared__ ushort As[128 * 32];
    __shared__ ushort Bs[128 * 32];

    const int tid = threadIdx.x;
    const int block_m = blockIdx.y * 128;
    const int block_n = blockIdx.x * 128;
    const int wave = tid >> 6, lane = tid & 63;
    const int wm = (wave >> 1) * 64, wn = (wave & 1) * 64;
    const int l15 = lane & 15, quad = lane >> 4;

    const int srow = wave * 32 + (lane >> 2);
    const int scol = (lane & 3) * 8;

    const ushort* gA0 = Xb + (size_t)(block_m + srow) * KDIM + scol;
    const ushort* gA1 = gA0 + 16 * KDIM;
    const int bc0 = min(block_n + srow, NFUSED - 1);
    const int bc1 = min(block_n + srow + 16, NFUSED - 1);
    const ushort* gB0 = Wb + (size_t)bc0 * KDIM + scol;
    const ushort* gB1 = Wb + (size_t)bc1 * KDIM + scol;

    ushort* lA0 = &As[(wave * 32) * 32];
    ushort* lA1 = &As[(wave * 32 + 16) * 32];
    ushort* lB0 = &Bs[(wave * 32) * 32];
    ushort* lB1 = &Bs[(wave * 32 + 16) * 32];

    floatx4 acc[4][4];
    #pragma unroll
    for (int i = 0; i < 4; ++i)
        #pragma unroll
        for (int j = 0; j < 4; ++j) {
            acc[i][j][0] = 0.f; acc[i][j][1] = 0.f;
            acc[i][j][2] = 0.f; acc[i][j][3] = 0.f;
        }

    for (int k0 = 0; k0 < KDIM; k0 += 32) {
        __builtin_amdgcn_global_load_lds(AS1C(gA0 + k0), AS3(lA0), 16, 0, 0);
        __builtin_amdgcn_global_load_lds(AS1C(gA1 + k0), AS3(lA1), 16, 0, 0);
        __builtin_amdgcn_global_load_lds(AS1C(gB0 + k0), AS3(lB0), 16, 0, 0);
        __builtin_amdgcn_global_load_lds(AS1C(gB1 + k0), AS3(lB1), 16, 0, 0);
        __syncthreads();

        short8 af[4], bfr[4];
        #pragma unroll
        for (int f = 0; f < 4; ++f) {
            af[f]  = *(const short8*)&As[(wm + f * 16 + l15) * 32 + quad * 8];
            bfr[f] = *(const short8*)&Bs[(wn + f * 16 + l15) * 32 + quad * 8];
        }
        #pragma unroll
        for (int fm = 0; fm < 4; ++fm)
            #pragma unroll
            for (int fn = 0; fn < 4; ++fn)
                acc[fm][fn] = __builtin_amdgcn_mfma_f32_16x16x32_bf16(
                    af[fm], bfr[fn], acc[fm][fn], 0, 0, 0);
        __syncthreads();
    }

    // epilogue: C/D layout col=lane&15, row=quad*4+reg
    #pragma unroll
    for (int fn = 0; fn < 4; ++fn) {
        const int col = block_n + wn + fn * 16 + l15;
        if (col >= NFUSED) continue;
        const float bcol = (col < 256) ? bq[col]
                         : (col < 400) ? boff[col - 256]
                                       : bkv[col - 400];
        #pragma unroll
        for (int fm = 0; fm < 4; ++fm) {
            #pragma unroll
            for (int r = 0; r < 4; ++r) {
                const int row = block_m + wm + fm * 16 + quad * 4 + r;
                const float val = acc[fm][fn][r] + bcol;
                if (col < 256) {
                    qb[(size_t)row * DMODEL + col] = f2bf(val);
                } else if (col < 400) {
                    off[(size_t)row * 144 + (col - 256)] = tanhf(val) * 4.0f;
                } else {
                    const int kc = col - 400;            // 0..511
                    const int b = row / NTOK, n = row % NTOK;
                    const int hh = (kc >> 5) & 7, c = kc & 31;
                    const int vo = (kc >= 256) ? 32 : 0;
                    kvb[(((size_t)(b * NHEAD + hh)) * NTOK + n) * 64 + c + vo] = f2bf(val);
                }
            }
        }
    }
}

// ---------------------------------------------------------------------------
// Final GEMM: out = attnb @ Wout^T + bout, fp32 store. 128x64 tile -> 800
// blocks. 4 waves: wave w computes rows (w&1)*64, cols (w>>1)*32 (4x2 frags).
// ---------------------------------------------------------------------------
__global__ __launch_bounds__(256) void gemm_out(
    const ushort* __restrict__ Xb,
    const ushort* __restrict__ Wb,
    const float* __restrict__ bias,
    float* __restrict__ Y)
{
    __shared__ ushort As[128 * 32];
    __shared__ ushort Bs[64 * 32];

    const int tid = threadIdx.x;
    const int block_m = blockIdx.y * 128;
    const int block_n = blockIdx.x * 64;
    const int wave = tid >> 6, lane = tid & 63;
    const int wm = (wave & 1) * 64, wn = (wave >> 1) * 32;
    const int l15 = lane & 15, quad = lane >> 4;

    const int srow = wave * 32 + (lane >> 2);   // A rows
    const int scol = (lane & 3) * 8;
    const int srowB = wave * 16 + (lane >> 2);  // B rows 0..63

    const ushort* gA0 = Xb + (size_t)(block_m + srow) * KDIM + scol;
    const ushort* gA1 = gA0 + 16 * KDIM;
    const ushort* gB  = Wb + (size_t)(block_n + srowB) * KDIM + scol;

    ushort* lA0 = &As[(wave * 32) * 32];
    ushort* lA1 = &As[(wave * 32 + 16) * 32];
    ushort* lB  = &Bs[(wave * 16) * 32];

    floatx4 acc[4][2];
    #pragma unroll
    for (int i = 0; i < 4; ++i)
        #pragma unroll
        for (int j = 0; j < 2; ++j) {
            acc[i][j][0] = 0.f; acc[i][j][1] = 0.f;
            acc[i][j][2] = 0.f; acc[i][j][3] = 0.f;
        }

    for (int k0 = 0; k0 < KDIM; k0 += 32) {
        __builtin_amdgcn_global_load_lds(AS1C(gA0 + k0), AS3(lA0), 16, 0, 0);
        __builtin_amdgcn_global_load_lds(AS1C(gA1 + k0), AS3(lA1), 16, 0, 0);
        __builtin_amdgcn_global_load_lds(AS1C(gB  + k0), AS3(lB),  16, 0, 0);
        __syncthreads();

        short8 af[4], bfr[2];
        #pragma unroll
        for (int f = 0; f < 4; ++f)
            af[f] = *(const short8*)&As[(wm + f * 16 + l15) * 32 + quad * 8];
        #pragma unroll
        for (int f = 0; f < 2; ++f)
            bfr[f] = *(const short8*)&Bs[(wn + f * 16 + l15) * 32 + quad * 8];
        #pragma unroll
        for (int fm = 0; fm < 4; ++fm)
            #pragma unroll
            for (int fn = 0; fn < 2; ++fn)
                acc[fm][fn] = __builtin_amdgcn_mfma_f32_16x16x32_bf16(
                    af[fm], bfr[fn], acc[fm][fn], 0, 0, 0);
        __syncthreads();
    }

    #pragma unroll
    for (int fn = 0; fn < 2; ++fn) {
        const int col = block_n + wn + fn * 16 + l15;
        const float bcol = bias[col];
        #pragma unroll
        for (int fm = 0; fm < 4; ++fm) {
            #pragma unroll
            for (int r = 0; r < 4; ++r) {
                const int row = block_m + wm + fm * 16 + quad * 4 + r;
                Y[(size_t)row * DMODEL + col] = acc[fm][fn][r] + bcol;
            }
        }
    }
}

// ---------------------------------------------------------------------------
// Deformable sampling + online-softmax attention.
// Wave = 2 tokens x 8 heads x 4 lanes; lane owns 8 channels (16B loads).
// k/v interleaved per pixel: (B*H, N, 64) = [k0..k31 | v0..v31].
// ---------------------------------------------------------------------------
__global__ __launch_bounds__(256) void deform_attn(
    const ushort* __restrict__ qb,    // (M,256) bf16
    const float* __restrict__ off,    // (M,144) fp32 (tanh*4 applied)
    const ushort* __restrict__ kvb,   // (B*H,N,64) bf16 interleaved
    ushort* __restrict__ attnb)       // (M,256) bf16
{
    const int lane = threadIdx.x & 63;
    const int token = blockIdx.x * 8 + (threadIdx.x >> 6) * 2 + (lane >> 5);
    const int h = (lane >> 2) & 7, lc = lane & 3;
    const int b = token / NTOK, n = token % NTOK;

    const uint4 qu = *(const uint4*)(qb + (size_t)token * DMODEL + h * HDIM + lc * 8);
    float q[8]; unpack8(qu, q);

    const float* ob = off + (size_t)token * 144 + h * (NPTS * 2);
    float2 offs[NPTS];
    #pragma unroll
    for (int p = 0; p < NPTS; ++p) offs[p] = *(const float2*)(ob + 2 * p);

    const float bx = (float)(n % WSP), by = (float)(n / WSP);
    const ushort* kb = kvb + (size_t)(b * NHEAD + h) * NTOK * 64 + lc * 8;

    float m = -INFINITY, s = 0.f;
    float o[8];
    #pragma unroll
    for (int c = 0; c < 8; ++c) o[c] = 0.f;

    #pragma unroll
    for (int p = 0; p < NPTS; ++p) {
        const float sx = bx + offs[p].x, sy = by + offs[p].y;
        const float fx0 = floorf(sx), fy0 = floorf(sy);
        const float wx1 = sx - fx0, wx0 = 1.0f - wx1;
        const float wy1 = sy - fy0, wy0 = 1.0f - wy1;
        const int ix0 = (int)fx0, iy0 = (int)fy0;
        const int ix1 = ix0 + 1, iy1 = iy0 + 1;
        const bool vx0 = (ix0 >= 0) & (ix0 <= WSP - 1);
        const bool vx1 = (ix1 >= 0) & (ix1 <= WSP - 1);
        const bool vy0 = (iy0 >= 0) & (iy0 <= HSP - 1);
        const bool vy1 = (iy1 >= 0) & (iy1 <= HSP - 1);
        const int cx0 = min(max(ix0, 0), WSP - 1);
        const int cx1 = min(max(ix1, 0), WSP - 1);
        const int cy0 = min(max(iy0, 0), HSP - 1);
        const int cy1 = min(max(iy1, 0), HSP - 1);
        const float w00 = wx0 * wy0 * (float)(vx0 && vy0);
        const float w10 = wx1 * wy0 * (float)(vx1 && vy0);
        const float w01 = wx0 * wy1 * (float)(vx0 && vy1);
        const float w11 = wx1 * wy1 * (float)(vx1 && vy1);
        const int i00 = (cy0 * WSP + cx0) * 64;
        const int i10 = (cy0 * WSP + cx1) * 64;
        const int i01 = (cy1 * WSP + cx0) * 64;
        const int i11 = (cy1 * WSP + cx1) * 64;

        const uint4 ku0 = *(const uint4*)(kb + i00);
        const uint4 ku1 = *(const uint4*)(kb + i10);
        const uint4 ku2 = *(const uint4*)(kb + i01);
        const uint4 ku3 = *(const uint4*)(kb + i11);
        const uint4 vu0 = *(const uint4*)(kb + i00 + 32);
        const uint4 vu1 = *(const uint4*)(kb + i10 + 32);
        const uint4 vu2 = *(const uint4*)(kb + i01 + 32);
        const uint4 vu3 = *(const uint4*)(kb + i11 + 32);

        float kc[8], d00 = 0.f, d10 = 0.f, d01 = 0.f, d11 = 0.f;
        unpack8(ku0, kc);
        #pragma unroll
        for (int c = 0; c < 8; ++c) d00 = fmaf(q[c], kc[c], d00);
        unpack8(ku1, kc);
        #pragma unroll
        for (int c = 0; c < 8; ++c) d10 = fmaf(q[c], kc[c], d10);
        unpack8(ku2, kc);
        #pragma unroll
        for (int c = 0; c < 8; ++c) d01 = fmaf(q[c], kc[c], d01);
        unpack8(ku3, kc);
        #pragma unroll
        for (int c = 0; c < 8; ++c) d11 = fmaf(q[c], kc[c], d11);

        float part = w00 * d00 + w10 * d10 + w01 * d01 + w11 * d11;
        part += __shfl_xor(part, 1, 64);
        part += __shfl_xor(part, 2, 64);
        const float l = part * 0.17677669529663687f;   // 32^-0.5

        const float m1 = fmaxf(m, l);
        const float corr = __expf(m - m1);
        const float e = __expf(l - m1);
        s = fmaf(s, corr, e);
        m = m1;

        const float e00 = e * w00, e10 = e * w10, e01 = e * w01, e11 = e * w11;
        float v0[8], v1[8], v2[8], v3[8];
        unpack8(vu0, v0); unpack8(vu1, v1); unpack8(vu2, v2); unpack8(vu3, v3);
        #pragma unroll
        for (int c = 0; c < 8; ++c)
            o[c] = fmaf(o[c], corr,
                        fmaf(e00, v0[c], fmaf(e10, v1[c], fmaf(e01, v2[c], e11 * v3[c]))));
    }

    const float inv = 1.0f / s;
    uint4 ru;
    ru.x = (uint)f2bf(o[0] * inv) | ((uint)f2bf(o[1] * inv) << 16);
    ru.y = (uint)f2bf(o[2] * inv) | ((uint)f2bf(o[3] * inv) << 16);
    ru.z = (uint)f2bf(o[4] * inv) | ((uint)f2bf(o[5] * inv) << 16);
    ru.w = (uint)f2bf(o[6] * inv) | ((uint)f2bf(o[7] * inv) << 16);
    *(uint4*)(attnb + (size_t)token * DMODEL + h * HDIM + lc * 8) = ru;
}

// ---------------------------------------------------------------------------
extern "C" void kernel_launch(void* const* d_in, const int* in_sizes, int n_in,
                              void* d_out, int out_size, void* d_ws, size_t ws_size,
                              hipStream_t stream) {
    const float* x    = (const float*)d_in[0];
    const float* Wq   = (const float*)d_in[1];
    const float* bq   = (const float*)d_in[2];
    const float* Woff = (const float*)d_in[3];
    const float* boff = (const float*)d_in[4];
    const float* Wkv  = (const float*)d_in[5];
    const float* bkv  = (const float*)d_in[6];
    const float* Wout = (const float*)d_in[7];
    const float* bout = (const float*)d_in[8];

    // workspace layout (~68 MB)
    ushort* xb     = (ushort*)d_ws;                          // 6,553,600 (reused as attnb)
    ushort* qb     = xb + (size_t)MTOT * DMODEL;             // 6,553,600
    float*  off    = (float*)(qb + (size_t)MTOT * DMODEL);   // 3,686,400 fp32
    ushort* kvb    = (ushort*)(off + (size_t)MTOT * 144);    // 13,107,200 (interleaved k|v)
    ushort* wfused = kvb + (size_t)MTOT * 512;               // 233,472 (Wq|Woff|Wkv)
    ushort* woutb  = wfused + NFUSED * KDIM;                 // 65,536
    ushort* attnb  = xb;   // xb dead after gemm_fused

    cast_all<<<dim3(6692), dim3(256), 0, stream>>>(x, Wq, Woff, Wkv, Wout,
                                                   xb, wfused, woutb);
    gemm_fused<<<dim3(8, 200), dim3(256), 0, stream>>>(xb, wfused, bq, boff, bkv,
                                                       qb, off, kvb);
    deform_attn<<<dim3(3200), dim3(256), 0, stream>>>(qb, off, kvb, attnb);
    gemm_out<<<dim3(4, 200), dim3(256), 0, stream>>>(attnb, woutb, bout, (float*)d_out);
}